// Round 8
// baseline (385.667 us; speedup 1.0000x reference)
//
#include <hip/hip_runtime.h>
#include <math.h>

#define TOKENS   8192
#define HIDDEN   7168
#define NEXPERT  256
#define NGROUP   8
#define TOPKG    4
#define TOPK     8
#define SCALE    2.5f

// GEMM: 128x128 block, BK=32, split-K 4 via atomicAdd into d_out (R7: 32 MB
// writes, atomics benign; d_ws untouched -> its 147us poison-fill is harness-
// fixed). R8: depth-2 register prefetch -> issue-to-consume gap ~1 full
// iteration (~900+ cyc) >= HBM latency, removing the per-tile vmcnt stall
// that capped R7 at MfmaUtil 26%.
#define BM 128
#define BN 128
#define BK 32
#define KSPLIT 4
#define KPB (HIDDEN / KSPLIT)   // 1792
#define NT  (KPB / BK)          // 56 (even -> 2x unrolled ping-pong works)

// LDS layout (halves): addr(row,k,hl) = row*72 + (k>>3)*16 + hl*8 + (k&7).
// Row stride 72 halves = 144 B: 16B-aligned b128 frags, <=2-way bank aliasing.
#define RSTR 72

typedef _Float16 half8 __attribute__((ext_vector_type(8)));
typedef _Float16 half4 __attribute__((ext_vector_type(4)));
typedef float    floatx4 __attribute__((ext_vector_type(4)));

__device__ __forceinline__ void cvt_store(_Float16* __restrict__ H,
                                          int row, int k0, float4 v) {
    half4 h, l;
    h[0] = (_Float16)v.x; h[1] = (_Float16)v.y;
    h[2] = (_Float16)v.z; h[3] = (_Float16)v.w;
    l[0] = (_Float16)(v.x - (float)h[0]);
    l[1] = (_Float16)(v.y - (float)h[1]);
    l[2] = (_Float16)(v.z - (float)h[2]);
    l[3] = (_Float16)(v.w - (float)h[3]);
    const int base = row * RSTR + ((k0 >> 3) << 4) + (k0 & 7);
    *(half4*)&H[base]     = h;
    *(half4*)&H[base + 8] = l;
}

__global__ __launch_bounds__(256) void zero_kernel(float* __restrict__ O) {
    const int i = blockIdx.x * 256 + threadIdx.x;
    *(float4*)&O[(size_t)i * 4] = float4{0.f, 0.f, 0.f, 0.f};
}

// ---------------------------------------------------------------------------
// Gate GEMM via fp16-split 3-product MFMA (bit-exact through routing):
//   x = xh + xl (fp16 RNE), logit = sum xh*wh + xh*wl + xl*wh  (fp32 acc)
// Double-buffered LDS + depth-2 register prefetch; atomicAdd epilogue.
// ---------------------------------------------------------------------------
__global__ __launch_bounds__(256, 2) void gate_gemm_kernel(
    const float* __restrict__ X, const float* __restrict__ W,
    float* __restrict__ OUT)
{
    __shared__ _Float16 Ab[2][BM * RSTR];   // 2 x 18 KB
    __shared__ _Float16 Bb[2][BN * RSTR];   // 2 x 18 KB  -> 72 KB total

    const int tid = threadIdx.x;
    const int nb  = blockIdx.x * BN;
    const int mb  = blockIdx.y * BM;
    const int kb  = blockIdx.z * KPB;

    // staging map: 128x32 tile = 1024 float4; thread takes rows q*32+(t>>3),
    // k0=(t&7)*4, q=0..3
    const int srow = tid >> 3;            // 0..31 (+q*32)
    const int sk0  = (tid & 7) * 4;       // 0..28
    const float* Aptr = X + (size_t)(mb + srow) * HIDDEN + kb + sk0;
    const float* Bptr = W + (size_t)(nb + srow) * HIDDEN + kb + sk0;

    // 4 waves as 2x2; wave tile 64m x 64n; 4x4 16x16 frags per wave
    const int lane = tid & 63, wave = tid >> 6;
    const int wm = (wave >> 1) * 64, wn = (wave & 1) * 64;
    const int fr = lane & 15, quad = lane >> 4;

    floatx4 acc[4][4];
#pragma unroll
    for (int i = 0; i < 4; i++)
#pragma unroll
        for (int j = 0; j < 4; j++) acc[i][j] = floatx4{0.f, 0.f, 0.f, 0.f};

    // depth-2 prefetch registers (2 tiles in flight)
    float4 av0[4], bv0[4], av1[4], bv1[4];

    auto load_tile = [&](float4* av, float4* bv, int t) {
        const int o = t * BK;
#pragma unroll
        for (int q = 0; q < 4; q++) {
            av[q] = *(const float4*)(Aptr + o + (size_t)(q * 32) * HIDDEN);
            bv[q] = *(const float4*)(Bptr + o + (size_t)(q * 32) * HIDDEN);
        }
    };
    auto stage = [&](_Float16* A, _Float16* B, const float4* av,
                     const float4* bv) {
#pragma unroll
        for (int q = 0; q < 4; q++) {
            cvt_store(A, q * 32 + srow, sk0, av[q]);
            cvt_store(B, q * 32 + srow, sk0, bv[q]);
        }
    };
    auto compute = [&](const _Float16* __restrict__ Ac,
                       const _Float16* __restrict__ Bc) {
        half8 ah[4], al[4];
#pragma unroll
        for (int i = 0; i < 4; i++) {
            const int a = (wm + i * 16 + fr) * RSTR + quad * 16;
            ah[i] = *(const half8*)&Ac[a];
            al[i] = *(const half8*)&Ac[a + 8];
        }
#pragma unroll
        for (int j = 0; j < 4; j++) {
            const int b = (wn + j * 16 + fr) * RSTR + quad * 16;
            const half8 bh = *(const half8*)&Bc[b];
            const half8 bl = *(const half8*)&Bc[b + 8];
#pragma unroll
            for (int i = 0; i < 4; i++) {
                acc[i][j] = __builtin_amdgcn_mfma_f32_16x16x32_f16(
                    al[i], bh, acc[i][j], 0, 0, 0);
                acc[i][j] = __builtin_amdgcn_mfma_f32_16x16x32_f16(
                    ah[i], bl, acc[i][j], 0, 0, 0);
                acc[i][j] = __builtin_amdgcn_mfma_f32_16x16x32_f16(
                    ah[i], bh, acc[i][j], 0, 0, 0);
            }
        }
    };

    // prologue: tiles 0,1 in regs; tile 0 staged
    load_tile(av0, bv0, 0);
    load_tile(av1, bv1, 1);
    stage(Ab[0], Bb[0], av0, bv0);

#pragma unroll 1
    for (int t = 0; t < NT; t += 2) {
        // even tile t: consume LDS buf0; slot0 regs were consumed -> refill
        __syncthreads();
        if (t + 2 < NT) load_tile(av0, bv0, t + 2);
        compute(Ab[0], Bb[0]);
        stage(Ab[1], Bb[1], av1, bv1);          // tile t+1 (loaded 1 iter ago)

        // odd tile t+1: consume LDS buf1; slot1 regs consumed -> refill
        __syncthreads();
        if (t + 3 < NT) load_tile(av1, bv1, t + 3);
        compute(Ab[1], Bb[1]);
        if (t + 2 < NT) stage(Ab[0], Bb[0], av0, bv0);   // tile t+2
    }

    // epilogue: D row = token (quad*4+reg), col = expert (lane&15);
    // split-K accumulation via atomicAdd (R7-measured: ~32 MB HBM writes)
#pragma unroll
    for (int i = 0; i < 4; i++)
#pragma unroll
        for (int j = 0; j < 4; j++) {
            const int col = nb + wn + j * 16 + fr;
#pragma unroll
            for (int r = 0; r < 4; r++) {
                const int row = mb + wm + i * 16 + quad * 4 + r;
                atomicAdd(&OUT[(size_t)row * NEXPERT + col], acc[i][j][r]);
            }
        }
}

// ---------------------------------------------------------------------------
// Routing: one wave per token, in-place on d_out (logits -> gate weights).
// Sigmoid fused; exact jax semantics incl. lowest-index tie-breaks.
// ---------------------------------------------------------------------------
__global__ __launch_bounds__(256) void route_kernel(
    float* __restrict__ S, const float* __restrict__ bias)
{
    const int lane = threadIdx.x & 63;
    const int wave = threadIdx.x >> 6;
    const int t    = blockIdx.x * 4 + wave;

    const float4 lg4 = *(const float4*)&S[(size_t)t * NEXPERT + lane * 4];
    const float4 b4  = *(const float4*)&bias[lane * 4];
    float sc[4];
    sc[0] = 1.0f / (1.0f + expf(-lg4.x));
    sc[1] = 1.0f / (1.0f + expf(-lg4.y));
    sc[2] = 1.0f / (1.0f + expf(-lg4.z));
    sc[3] = 1.0f / (1.0f + expf(-lg4.w));
    float swb[4] = { sc[0] + b4.x, sc[1] + b4.y, sc[2] + b4.z, sc[3] + b4.w };

    // per-lane top-2 of 4
    float m1 = -INFINITY, m2 = -INFINITY;
#pragma unroll
    for (int j = 0; j < 4; j++) {
        const float v = swb[j];
        if (v > m1)      { m2 = m1; m1 = v; }
        else if (v > m2) { m2 = v; }
    }
    // merge across the 8 lanes of my group
#pragma unroll
    for (int s = 1; s < 8; s <<= 1) {
        const float o1 = __shfl_xor(m1, s, 64);
        const float o2 = __shfl_xor(m2, s, 64);
        const float hi = fmaxf(m1, o1);
        const float lo = fminf(m1, o1);
        m2 = fmaxf(lo, fmaxf(m2, o2));
        m1 = hi;
    }
    const float gs = m1 + m2;

    // top-4 groups by rank (tie -> lower group index)
    float gsc[NGROUP];
#pragma unroll
    for (int g = 0; g < NGROUP; g++) gsc[g] = __shfl(gs, g * 8, 64);
    const int myg = lane >> 3;
    int rank = 0;
#pragma unroll
    for (int g = 0; g < NGROUP; g++)
        rank += (gsc[g] > gs) || (gsc[g] == gs && g < myg);
    const bool kept = (rank < TOPKG);

    float v[4];
#pragma unroll
    for (int j = 0; j < 4; j++) v[j] = kept ? swb[j] : 0.0f;

    // top-8 experts: 8 rounds of wave argmax (lowest idx on ties)
    float sum = 0.0f;
    int selmask = 0;
    for (int r = 0; r < TOPK; r++) {
        float bv = -INFINITY;
        int   bi = 0x7fffffff;
#pragma unroll
        for (int j = 0; j < 4; j++) {
            const bool avail = ((selmask >> j) & 1) == 0;
            if (avail && v[j] > bv) { bv = v[j]; bi = lane * 4 + j; }
        }
#pragma unroll
        for (int s = 1; s < 64; s <<= 1) {
            const float ov = __shfl_xor(bv, s, 64);
            const int   oi = __shfl_xor(bi, s, 64);
            if (ov > bv || (ov == bv && oi < bi)) { bv = ov; bi = oi; }
        }
        const int wl = bi >> 2, wj = bi & 3;
        const float mysc = (wj == 0) ? sc[0] : (wj == 1) ? sc[1]
                         : (wj == 2) ? sc[2] : sc[3];
        sum += __shfl(mysc, wl, 64);
        if (lane == wl) selmask |= (1 << wj);
    }

    const float rcp = SCALE / (sum + 1e-20f);
    float4 o;
    o.x = (selmask & 1) ? sc[0] * rcp : 0.0f;
    o.y = (selmask & 2) ? sc[1] * rcp : 0.0f;
    o.z = (selmask & 4) ? sc[2] * rcp : 0.0f;
    o.w = (selmask & 8) ? sc[3] * rcp : 0.0f;
    *(float4*)&S[(size_t)t * NEXPERT + lane * 4] = o;
}

extern "C" void kernel_launch(void* const* d_in, const int* in_sizes, int n_in,
                              void* d_out, int out_size, void* d_ws, size_t ws_size,
                              hipStream_t stream) {
    const float* X    = (const float*)d_in[0];   // [8192, 7168]
    const float* W    = (const float*)d_in[1];   // [256, 7168]
    const float* bias = (const float*)d_in[2];   // [256]
    float* out = (float*)d_out;                  // [8192, 256]
    (void)d_ws; (void)ws_size;   // unused: d_ws poison-fill costs 147us of
                                 // harness overhead regardless; reading it
                                 // additionally collides with kernel traffic

    zero_kernel<<<(TOKENS * NEXPERT / 4) / 256, 256, 0, stream>>>(out);
    dim3 ggrid(NEXPERT / BN, TOKENS / BM, KSPLIT);   // (2, 64, 4) = 512 blocks
    gate_gemm_kernel<<<ggrid, 256, 0, stream>>>(X, W, out);
    route_kernel<<<TOKENS / 4, 256, 0, stream>>>(out, bias);
}